// Round 8
// baseline (2112.726 us; speedup 1.0000x reference)
//
#include <hip/hip_runtime.h>
#include <hip/hip_bf16.h>
#include <cstdint>
#include <cstddef>

// =====================================================================
// FullRankRNN on MI355X — R3-verified exchange protocol, swapped-MFMA
// register publish (R7), + R8: ballot poll (4x less MALL poll traffic)
// and store-order fix (publish+hbuf acks drain in parallel, hbuf ack no
// longer serialized into the next poll's vmcnt(0)).
// =====================================================================

static constexpr int B = 64, T = 512, I = 128, L = 1024, O = 128;
static constexpr float C_NOISE = 0.05f, C_GAMMA = 0.2f;

static constexpr int NROW = 4, BT = 16, NJB = 16, JT = 64;

// ---------------- workspace layout (bytes) ----------------
static constexpr size_t WREC_OFF = 0;                              // L*L bf16
static constexpr size_t WIT_OFF  = WREC_OFF + (size_t)L * L * 2;   // wiT[l][i]*si
static constexpr size_t WOT_OFF  = WIT_OFF + (size_t)L * I * 2;    // woT[o][l]*so
static constexpr size_t RBUF_OFF = WOT_OFF + (size_t)O * L * 2;    // 2 x B x L bf16
static constexpr size_t FLAG_OFF = RBUF_OFF + (size_t)2 * B * L * 2;
static constexpr size_t NFLAGS   = (size_t)NROW * (T + 1) * NJB * 4;   // per-wave flags
static constexpr size_t FLAG_BYTES = NFLAGS * 4;
static constexpr size_t HBUF_OFF = ((FLAG_OFF + FLAG_BYTES + 511) / 512) * 512;
static constexpr size_t WS_NEED  = HBUF_OFF + (size_t)B * T * L * 2;

typedef __attribute__((ext_vector_type(8))) short s16x8;
typedef __attribute__((ext_vector_type(4))) float f32x4;
typedef __attribute__((ext_vector_type(4))) unsigned int u32x4;
typedef __attribute__((ext_vector_type(2))) unsigned long long u64x2;

__device__ __forceinline__ float fexp2(float x) {
#if __has_builtin(__builtin_amdgcn_exp2f)
  return __builtin_amdgcn_exp2f(x);
#else
  return exp2f(x);
#endif
}
__device__ __forceinline__ float frcp(float x) {
#if __has_builtin(__builtin_amdgcn_rcpf)
  return __builtin_amdgcn_rcpf(x);
#else
  return 1.0f / x;
#endif
}
__device__ __forceinline__ float fast_tanh(float x) {
  float e = fexp2(x * 2.8853900817779268f);
  return 1.0f - 2.0f * frcp(e + 1.0f);
}
__device__ __forceinline__ uint16_t bf16bits(float x) {
  __hip_bfloat16 h = __float2bfloat16(x);
  return *reinterpret_cast<uint16_t*>(&h);
}

// ---------------------------------------------------------------------
__global__ void pack_kernel(const float* __restrict__ wi, const float* __restrict__ si,
                            const float* __restrict__ wrec,
                            const float* __restrict__ wo, const float* __restrict__ so,
                            uint8_t* __restrict__ ws) {
  int idx = blockIdx.x * blockDim.x + threadIdx.x;
  int stride = gridDim.x * blockDim.x;

  __hip_bfloat16* wrecb = (__hip_bfloat16*)(ws + WREC_OFF);
  for (int i = idx; i < L * L; i += stride) wrecb[i] = __float2bfloat16(wrec[i]);

  __hip_bfloat16* wit = (__hip_bfloat16*)(ws + WIT_OFF);
  for (int n = idx; n < L * I; n += stride) {
    int l = n >> 7, ii = n & 127;
    wit[n] = __float2bfloat16(wi[(size_t)ii * L + l] * si[ii]);
  }
  __hip_bfloat16* wot = (__hip_bfloat16*)(ws + WOT_OFF);
  for (int n = idx; n < O * L; n += stride) {
    int o = n >> 10, l = n & 1023;
    wot[n] = __float2bfloat16(wo[(size_t)l * O + o] * so[o]);
  }
  uint32_t* flags = (uint32_t*)(ws + FLAG_OFF);
  for (size_t n = idx; n < NFLAGS; n += stride) flags[n] = 0;
}

// ---------------------------------------------------------------------
__launch_bounds__(256, 1)
__global__ void rnn_kernel(const float* __restrict__ input, const float* __restrict__ noise,
                           const float* __restrict__ bvec, const float* __restrict__ h0,
                           uint8_t* __restrict__ ws) {
  const int tid  = threadIdx.x;
  const int lane = tid & 63;
  const int w    = tid >> 6;
  const int bx   = blockIdx.x;
  const int row  = bx & 3;
  const int jblk = bx >> 2;
  const int b0   = row * BT;
  const int j0   = jblk * JT;
  const int l15  = lane & 15;
  const int lhi  = lane >> 4;

  // swapped-C layout: this lane owns batch (b0+l15), cols jc0..jc0+3
  const int jc0  = j0 + w * 16 + lhi * 4;
  const int mybatch = b0 + l15;

  const short* wrecb = (const short*)(ws + WREC_OFF);
  const short* wit   = (const short*)(ws + WIT_OFF);
  uint64_t* rbuf     = (uint64_t*)(ws + RBUF_OFF);   // 8B granules [parity][b][l/4]
  uint32_t* flags    = (uint32_t*)(ws + FLAG_OFF);
  __hip_bfloat16* hbuf = (__hip_bfloat16*)(ws + HBUF_OFF);

  __shared__ __align__(16) uint8_t ldsA[2][16 * 2048];   // double-buffered r tile

  // stationary weights (fragment layout identical for A- or B-operand use)
  s16x8 wfrag[32];
  #pragma unroll
  for (int kt = 0; kt < 32; ++kt)
    wfrag[kt] = *(const s16x8*)(wrecb + (size_t)(j0 + w * 16 + l15) * L + kt * 32 + lhi * 8);
  s16x8 wifrag[4];
  #pragma unroll
  for (int kt = 0; kt < 4; ++kt)
    wifrag[kt] = *(const s16x8*)(wit + (size_t)(j0 + w * 16 + l15) * I + kt * 32 + lhi * 8);

  f32x4 bias, h;
  #pragma unroll
  for (int q = 0; q < 4; ++q) { bias[q] = bvec[jc0 + q]; h[q] = h0[jc0 + q]; }

  // gather-side constants
  const int grow = tid >> 4;        // batch row 0..15
  const int gseg = tid & 15;        // source col-block 0..15 (one 128B chunk)
  const int gsw  = (grow ^ gseg) & 7;

  // ---- init: publish r_0 = tanh(h0) straight from registers ----
  {
    uint64_t pv = 0;
    #pragma unroll
    for (int q = 0; q < 4; ++q)
      pv |= (uint64_t)bf16bits(fast_tanh(h0[jc0 + q])) << (16 * q);
    size_t slot = (size_t)mybatch * (L / 4) + (size_t)(jc0 >> 2);
    __hip_atomic_store(&rbuf[slot], pv, __ATOMIC_RELAXED, __HIP_MEMORY_SCOPE_AGENT);
    __builtin_amdgcn_s_waitcnt(0);
    if (lane == 0)
      __hip_atomic_store(&flags[((size_t)(row * (T + 1) + 0) * NJB + jblk) * 4 + w], 1u,
                         __ATOMIC_RELAXED, __HIP_MEMORY_SCOPE_AGENT);
  }

  for (int t = 0; t < T; ++t) {
    // ---- P0: input prefetch + bf16 conversion (lane l15 = batch) ----
    f32x4 inLo[4], inHi[4];
    #pragma unroll
    for (int kt = 0; kt < 4; ++kt) {
      const float* p = input + ((size_t)(b0 + l15) * T + t) * I + kt * 32 + lhi * 8;
      inLo[kt] = *(const f32x4*)p;
      inHi[kt] = *(const f32x4*)(p + 4);
    }
    f32x4 nz = *(const f32x4*)(noise + ((size_t)mybatch * T + t) * L + jc0);
    s16x8 af[4];
    #pragma unroll
    for (int kt = 0; kt < 4; ++kt)
      #pragma unroll
      for (int q = 0; q < 4; ++q) {
        af[kt][q]     = (short)bf16bits(inLo[kt][q]);
        af[kt][q + 4] = (short)bf16bits(inHi[kt][q]);
      }

    // ---- P0.5: seed acc with input projection (off critical path) ----
    f32x4 acc0 = {0.f,0.f,0.f,0.f}, acc1 = {0.f,0.f,0.f,0.f};
    f32x4 acc2 = {0.f,0.f,0.f,0.f}, acc3 = {0.f,0.f,0.f,0.f};
    acc0 = __builtin_amdgcn_mfma_f32_16x16x32_bf16(wifrag[0], af[0], acc0, 0, 0, 0);
    acc1 = __builtin_amdgcn_mfma_f32_16x16x32_bf16(wifrag[1], af[1], acc1, 0, 0, 0);
    acc2 = __builtin_amdgcn_mfma_f32_16x16x32_bf16(wifrag[2], af[2], acc2, 0, 0, 0);
    acc3 = __builtin_amdgcn_mfma_f32_16x16x32_bf16(wifrag[3], af[3], acc3, 0, 0, 0);

    // ---- P1: ballot poll — lanes 0..15 each certify one source block ----
    {
      const uint32_t* fp = flags + ((size_t)(row * (T + 1) + t) * NJB + l15) * 4;
      bool need = (lane < 16);
      while (true) {
        uint32_t ok = 1u;
        if (need) {
          u32x4 f4;
          asm volatile("global_load_dwordx4 %0, %1, off sc0 sc1\n\ts_waitcnt vmcnt(0)"
                       : "=&v"(f4) : "v"(fp) : "memory");
          ok = ((f4.x & f4.y & f4.z & f4.w) != 0u) ? 1u : 0u;
          if (ok) need = false;
        }
        if (__all(ok)) break;
      }
    }

    // ---- P2: coherent gather + swizzled LDS write (R3-verified) ----
    {
      const uint8_t* src = (const uint8_t*)rbuf
                         + (size_t)(t & 1) * (B * L * 2)
                         + (size_t)(b0 + grow) * 2048 + (size_t)gseg * 128;
      u64x2 v[8];
      #pragma unroll
      for (int i = 0; i < 8; ++i)
        asm volatile("global_load_dwordx4 %0, %1, off sc0 sc1"
                     : "=&v"(v[i]) : "v"(src + i * 16) : "memory");
      asm volatile("s_waitcnt vmcnt(0)" ::: "memory");
      __builtin_amdgcn_sched_barrier(0);
      uint8_t* dst = ldsA[t & 1] + grow * 2048 + gseg * 128;
      #pragma unroll
      for (int i = 0; i < 8; ++i)
        *(u64x2*)(dst + ((i ^ gsw) * 16)) = v[i];
    }
    __syncthreads();   // the ONLY barrier per step

    // ---- P3: acc += W_slice^T x r_t  (A=wfrag, B=r-frag; 4 chains) ----
    const uint8_t* Ab = ldsA[t & 1];
    #pragma unroll
    for (int kt = 0; kt < 32; ++kt) {
      int slot = ((kt * 4 + lhi) ^ ((l15 ^ (kt >> 1)) & 7)) * 16;
      s16x8 a = *(const s16x8*)(Ab + l15 * 2048 + slot);
      switch (kt & 3) {
        case 0: acc0 = __builtin_amdgcn_mfma_f32_16x16x32_bf16(wfrag[kt], a, acc0, 0, 0, 0); break;
        case 1: acc1 = __builtin_amdgcn_mfma_f32_16x16x32_bf16(wfrag[kt], a, acc1, 0, 0, 0); break;
        case 2: acc2 = __builtin_amdgcn_mfma_f32_16x16x32_bf16(wfrag[kt], a, acc2, 0, 0, 0); break;
        default: acc3 = __builtin_amdgcn_mfma_f32_16x16x32_bf16(wfrag[kt], a, acc3, 0, 0, 0); break;
      }
    }

    // ---- P4: h update; publish r_{t+1}; overlap acks; flag last ----
    uint64_t pv = 0;
    #pragma unroll
    for (int q = 0; q < 4; ++q) {
      float hn = 0.8f * h[q] + C_GAMMA * ((acc0[q] + acc1[q]) + (acc2[q] + acc3[q]))
               + C_NOISE * nz[q];
      h[q] = hn;
      pv |= (uint64_t)bf16bits(fast_tanh(hn + bias[q])) << (16 * q);
    }
    {
      size_t slot = (size_t)((t + 1) & 1) * (B * L / 4)
                  + (size_t)mybatch * (L / 4) + (size_t)(jc0 >> 2);
      __hip_atomic_store(&rbuf[slot], pv, __ATOMIC_RELAXED, __HIP_MEMORY_SCOPE_AGENT);
    }
    // hv pack + hbuf store overlap the publish ack; one vmcnt drains both
    {
      uint64_t hv = 0;
      #pragma unroll
      for (int q = 0; q < 4; ++q)
        hv |= (uint64_t)bf16bits(fast_tanh(h[q])) << (16 * q);
      *(uint64_t*)(hbuf + ((size_t)mybatch * T + t) * L + jc0) = hv;
    }
    __builtin_amdgcn_s_waitcnt(0);
    if (lane == 0)
      __hip_atomic_store(&flags[((size_t)(row * (T + 1) + (t + 1)) * NJB + jblk) * 4 + w], 1u,
                         __ATOMIC_RELAXED, __HIP_MEMORY_SCOPE_AGENT);
  }
}

// ---------------------------------------------------------------------
__launch_bounds__(256)
__global__ void out_gemm(const uint8_t* __restrict__ ws, float* __restrict__ out) {
  const short* hs  = (const short*)(ws + HBUF_OFF);
  const short* wot = (const short*)(ws + WOT_OFF);
  const int tid = threadIdx.x, lane = tid & 63, w = tid >> 6;
  const int wm = w >> 1, wn = w & 1;
  const int l15 = lane & 15, lhi = lane >> 4;
  const size_t m0 = (size_t)blockIdx.x * 128 + (size_t)wm * 64;

  f32x4 acc[4][4] = {};
  for (int kt = 0; kt < 32; ++kt) {
    s16x8 a[4], b[4];
    #pragma unroll
    for (int fi = 0; fi < 4; ++fi)
      a[fi] = *(const s16x8*)(hs + (m0 + fi * 16 + l15) * L + kt * 32 + lhi * 8);
    #pragma unroll
    for (int fj = 0; fj < 4; ++fj)
      b[fj] = *(const s16x8*)(wot + (size_t)(wn * 64 + fj * 16 + l15) * L + kt * 32 + lhi * 8);
    #pragma unroll
    for (int fi = 0; fi < 4; ++fi)
      #pragma unroll
      for (int fj = 0; fj < 4; ++fj)
        acc[fi][fj] = __builtin_amdgcn_mfma_f32_16x16x32_bf16(a[fi], b[fj], acc[fi][fj], 0, 0, 0);
  }
  #pragma unroll
  for (int fi = 0; fi < 4; ++fi)
    #pragma unroll
    for (int fj = 0; fj < 4; ++fj)
      #pragma unroll
      for (int q = 0; q < 4; ++q) {
        size_t m = m0 + fi * 16 + lhi * 4 + q;
        out[m * O + wn * 64 + fj * 16 + l15] = acc[fi][fj][q];
      }
}

__global__ void ws_too_small(float* out, int n) {
  int i = blockIdx.x * blockDim.x + threadIdx.x;
  if (i < n) out[i] = 12345.0f;
}

extern "C" void kernel_launch(void* const* d_in, const int* in_sizes, int n_in,
                              void* d_out, int out_size, void* d_ws, size_t ws_size,
                              hipStream_t stream) {
  const float* input = (const float*)d_in[0];
  const float* noise = (const float*)d_in[1];
  const float* wi    = (const float*)d_in[2];
  const float* si    = (const float*)d_in[3];
  const float* wrec  = (const float*)d_in[4];
  const float* bvec  = (const float*)d_in[5];
  const float* wo    = (const float*)d_in[6];
  const float* so    = (const float*)d_in[7];
  const float* h0    = (const float*)d_in[8];
  uint8_t* ws = (uint8_t*)d_ws;
  float* out = (float*)d_out;

  if (ws_size < WS_NEED) {
    ws_too_small<<<(out_size + 255) / 256, 256, 0, stream>>>(out, out_size);
    return;
  }

  pack_kernel<<<256, 256, 0, stream>>>(wi, si, wrec, wo, so, ws);
  rnn_kernel<<<NROW * NJB, 256, 0, stream>>>(input, noise, bvec, h0, ws);
  out_gemm<<<(B * T) / 128, 256, 0, stream>>>(ws, out);
}

// Round 9
// 2052.338 us; speedup vs baseline: 1.0294x; 1.0294x over previous
//
#include <hip/hip_runtime.h>
#include <hip/hip_bf16.h>
#include <cstdint>
#include <cstddef>

// =====================================================================
// FullRankRNN on MI355X — in-band stamp exchange (flag == data bit).
//  Base: R7 (verified, 2095us). Change: eliminate publish-ack + flag
//  round trips. r granule = 4 bf16 (8B); bit0 of col0's bf16 carries the
//  step stamp s(k) = ((k>>1)&1)^1 (period 4; ABA-safe; != zero-init).
//  Producer: ONE relaxed-agent 8B atomic store per granule. Consumer:
//  R7's proven asm gather (8x contiguous dwordx4 sc0sc1 + vmcnt(0))
//  looped until all 16 stamp bits match — the poll IS the gather.
//  Bounded spin -> protocol failure = fast wrong answer, not a hang.
// =====================================================================

static constexpr int B = 64, T = 512, I = 128, L = 1024, O = 128;
static constexpr float C_NOISE = 0.05f, C_GAMMA = 0.2f;

static constexpr int NROW = 4, BT = 16, NJB = 16, JT = 64;

// ---------------- workspace layout (bytes) ----------------
static constexpr size_t WREC_OFF = 0;                              // L*L bf16
static constexpr size_t WIT_OFF  = WREC_OFF + (size_t)L * L * 2;   // wiT[l][i]*si
static constexpr size_t WOT_OFF  = WIT_OFF + (size_t)L * I * 2;    // woT[o][l]*so
static constexpr size_t RBUF_OFF = WOT_OFF + (size_t)O * L * 2;    // 2 x B x L bf16
static constexpr size_t RBUF_BYTES = (size_t)2 * B * L * 2;        // 256 KiB
static constexpr size_t HBUF_OFF = ((RBUF_OFF + RBUF_BYTES + 131072 + 511) / 512) * 512;
static constexpr size_t WS_NEED  = HBUF_OFF + (size_t)B * T * L * 2;

typedef __attribute__((ext_vector_type(8))) short s16x8;
typedef __attribute__((ext_vector_type(4))) float f32x4;
typedef __attribute__((ext_vector_type(2))) unsigned long long u64x2;

__device__ __forceinline__ float fexp2(float x) {
#if __has_builtin(__builtin_amdgcn_exp2f)
  return __builtin_amdgcn_exp2f(x);
#else
  return exp2f(x);
#endif
}
__device__ __forceinline__ float frcp(float x) {
#if __has_builtin(__builtin_amdgcn_rcpf)
  return __builtin_amdgcn_rcpf(x);
#else
  return 1.0f / x;
#endif
}
__device__ __forceinline__ float fast_tanh(float x) {
  float e = fexp2(x * 2.8853900817779268f);
  return 1.0f - 2.0f * frcp(e + 1.0f);
}
__device__ __forceinline__ uint16_t bf16bits(float x) {
  __hip_bfloat16 h = __float2bfloat16(x);
  return *reinterpret_cast<uint16_t*>(&h);
}

// ---------------------------------------------------------------------
__global__ void pack_kernel(const float* __restrict__ wi, const float* __restrict__ si,
                            const float* __restrict__ wrec,
                            const float* __restrict__ wo, const float* __restrict__ so,
                            uint8_t* __restrict__ ws) {
  int idx = blockIdx.x * blockDim.x + threadIdx.x;
  int stride = gridDim.x * blockDim.x;

  __hip_bfloat16* wrecb = (__hip_bfloat16*)(ws + WREC_OFF);
  for (int i = idx; i < L * L; i += stride) wrecb[i] = __float2bfloat16(wrec[i]);

  __hip_bfloat16* wit = (__hip_bfloat16*)(ws + WIT_OFF);
  for (int n = idx; n < L * I; n += stride) {
    int l = n >> 7, ii = n & 127;
    wit[n] = __float2bfloat16(wi[(size_t)ii * L + l] * si[ii]);
  }
  __hip_bfloat16* wot = (__hip_bfloat16*)(ws + WOT_OFF);
  for (int n = idx; n < O * L; n += stride) {
    int o = n >> 10, l = n & 1023;
    wot[n] = __float2bfloat16(wo[(size_t)l * O + o] * so[o]);
  }
  // zero rbuf (both parities) -> stamp bits reset, no cross-call state
  uint32_t* rb = (uint32_t*)(ws + RBUF_OFF);
  for (size_t n = idx; n < RBUF_BYTES / 4; n += stride) rb[n] = 0;
}

// ---------------------------------------------------------------------
__launch_bounds__(256, 1)
__global__ void rnn_kernel(const float* __restrict__ input, const float* __restrict__ noise,
                           const float* __restrict__ bvec, const float* __restrict__ h0,
                           uint8_t* __restrict__ ws) {
  const int tid  = threadIdx.x;
  const int lane = tid & 63;
  const int w    = tid >> 6;
  const int bx   = blockIdx.x;
  const int row  = bx & 3;
  const int jblk = bx >> 2;
  const int b0   = row * BT;
  const int j0   = jblk * JT;
  const int l15  = lane & 15;
  const int lhi  = lane >> 4;

  // swapped-C layout: this lane owns batch (b0+l15), cols jc0..jc0+3
  const int jc0  = j0 + w * 16 + lhi * 4;
  const int mybatch = b0 + l15;

  const short* wrecb = (const short*)(ws + WREC_OFF);
  const short* wit   = (const short*)(ws + WIT_OFF);
  uint64_t* rbuf     = (uint64_t*)(ws + RBUF_OFF);   // 8B granules [parity][b][l/4]
  __hip_bfloat16* hbuf = (__hip_bfloat16*)(ws + HBUF_OFF);

  __shared__ __align__(16) uint8_t ldsA[2][16 * 2048];   // double-buffered r tile

  // stationary weights (fragment layout identical for A- or B-operand use)
  s16x8 wfrag[32];
  #pragma unroll
  for (int kt = 0; kt < 32; ++kt)
    wfrag[kt] = *(const s16x8*)(wrecb + (size_t)(j0 + w * 16 + l15) * L + kt * 32 + lhi * 8);
  s16x8 wifrag[4];
  #pragma unroll
  for (int kt = 0; kt < 4; ++kt)
    wifrag[kt] = *(const s16x8*)(wit + (size_t)(j0 + w * 16 + l15) * I + kt * 32 + lhi * 8);

  f32x4 bias, h;
  #pragma unroll
  for (int q = 0; q < 4; ++q) { bias[q] = bvec[jc0 + q]; h[q] = h0[jc0 + q]; }

  // gather-side constants
  const int grow = tid >> 4;        // batch row 0..15
  const int gseg = tid & 15;        // 128B chunk within the batch row
  const int gsw  = (grow ^ gseg) & 7;

  // ---- init: publish r_0 = tanh(h0) with stamp s(0)=1, parity 0 ----
  {
    uint64_t pv = 0;
    #pragma unroll
    for (int q = 0; q < 4; ++q)
      pv |= (uint64_t)bf16bits(fast_tanh(h0[jc0 + q])) << (16 * q);
    pv = (pv & ~1ull) | 1ull;   // stamp bit for k=0
    size_t slot = (size_t)mybatch * (L / 4) + (size_t)(jc0 >> 2);
    __hip_atomic_store(&rbuf[slot], pv, __ATOMIC_RELAXED, __HIP_MEMORY_SCOPE_AGENT);
  }

  for (int t = 0; t < T; ++t) {
    // ---- P0: input prefetch + bf16 conversion (lane l15 = batch) ----
    f32x4 inLo[4], inHi[4];
    #pragma unroll
    for (int kt = 0; kt < 4; ++kt) {
      const float* p = input + ((size_t)(b0 + l15) * T + t) * I + kt * 32 + lhi * 8;
      inLo[kt] = *(const f32x4*)p;
      inHi[kt] = *(const f32x4*)(p + 4);
    }
    f32x4 nz = *(const f32x4*)(noise + ((size_t)mybatch * T + t) * L + jc0);
    s16x8 af[4];
    #pragma unroll
    for (int kt = 0; kt < 4; ++kt)
      #pragma unroll
      for (int q = 0; q < 4; ++q) {
        af[kt][q]     = (short)bf16bits(inLo[kt][q]);
        af[kt][q + 4] = (short)bf16bits(inHi[kt][q]);
      }

    // ---- P0.5: seed acc with input projection (off critical path) ----
    f32x4 acc0 = {0.f,0.f,0.f,0.f}, acc1 = {0.f,0.f,0.f,0.f};
    f32x4 acc2 = {0.f,0.f,0.f,0.f}, acc3 = {0.f,0.f,0.f,0.f};
    acc0 = __builtin_amdgcn_mfma_f32_16x16x32_bf16(wifrag[0], af[0], acc0, 0, 0, 0);
    acc1 = __builtin_amdgcn_mfma_f32_16x16x32_bf16(wifrag[1], af[1], acc1, 0, 0, 0);
    acc2 = __builtin_amdgcn_mfma_f32_16x16x32_bf16(wifrag[2], af[2], acc2, 0, 0, 0);
    acc3 = __builtin_amdgcn_mfma_f32_16x16x32_bf16(wifrag[3], af[3], acc3, 0, 0, 0);

    // ---- P1+P2: stamped gather — poll IS the gather (R7 asm body) ----
    u64x2 v[8];
    {
      const uint64_t want = (uint64_t)(((t >> 1) & 1) ^ 1);  // s(t)
      const uint8_t* src = (const uint8_t*)rbuf
                         + (size_t)(t & 1) * (B * L * 2)
                         + (size_t)(b0 + grow) * 2048 + (size_t)gseg * 128;
      uint32_t spin = 0;
      uint64_t bad;
      do {
        #pragma unroll
        for (int i = 0; i < 8; ++i)
          asm volatile("global_load_dwordx4 %0, %1, off sc0 sc1"
                       : "=&v"(v[i]) : "v"(src + i * 16) : "memory");
        asm volatile("s_waitcnt vmcnt(0)" ::: "memory");
        bad = 0;
        #pragma unroll
        for (int i = 0; i < 8; ++i)
          bad |= (v[i].x ^ want) | (v[i].y ^ want);
        bad &= 1ull;
      } while (bad && (++spin < (1u << 18)));
      __builtin_amdgcn_sched_barrier(0);
      uint8_t* dst = ldsA[t & 1] + grow * 2048 + gseg * 128;
      #pragma unroll
      for (int i = 0; i < 8; ++i)
        *(u64x2*)(dst + ((i ^ gsw) * 16)) = v[i];
    }
    __syncthreads();   // the ONLY barrier per step

    // ---- P3: acc += W_slice^T x r_t  (A=wfrag, B=r-frag; 4 chains) ----
    const uint8_t* Ab = ldsA[t & 1];
    #pragma unroll
    for (int kt = 0; kt < 32; ++kt) {
      int slot = ((kt * 4 + lhi) ^ ((l15 ^ (kt >> 1)) & 7)) * 16;
      s16x8 a = *(const s16x8*)(Ab + l15 * 2048 + slot);
      switch (kt & 3) {
        case 0: acc0 = __builtin_amdgcn_mfma_f32_16x16x32_bf16(wfrag[kt], a, acc0, 0, 0, 0); break;
        case 1: acc1 = __builtin_amdgcn_mfma_f32_16x16x32_bf16(wfrag[kt], a, acc1, 0, 0, 0); break;
        case 2: acc2 = __builtin_amdgcn_mfma_f32_16x16x32_bf16(wfrag[kt], a, acc2, 0, 0, 0); break;
        default: acc3 = __builtin_amdgcn_mfma_f32_16x16x32_bf16(wfrag[kt], a, acc3, 0, 0, 0); break;
      }
    }

    // ---- P4: h update; stamped publish straight from registers ----
    uint64_t pv = 0;
    #pragma unroll
    for (int q = 0; q < 4; ++q) {
      float hn = 0.8f * h[q] + C_GAMMA * ((acc0[q] + acc1[q]) + (acc2[q] + acc3[q]))
               + C_NOISE * nz[q];
      h[q] = hn;
      pv |= (uint64_t)bf16bits(fast_tanh(hn + bias[q])) << (16 * q);
    }
    {
      const uint64_t sb = (uint64_t)((((t + 1) >> 1) & 1) ^ 1);  // s(t+1)
      pv = (pv & ~1ull) | sb;
      size_t slot = (size_t)((t + 1) & 1) * (B * L / 4)
                  + (size_t)mybatch * (L / 4) + (size_t)(jc0 >> 2);
      __hip_atomic_store(&rbuf[slot], pv, __ATOMIC_RELAXED, __HIP_MEMORY_SCOPE_AGENT);
    }
    // no ack wait, no flag — stamp travels with the data

    // ---- off-critical-path: hbuf as one 8B store ----
    {
      uint64_t hv = 0;
      #pragma unroll
      for (int q = 0; q < 4; ++q)
        hv |= (uint64_t)bf16bits(fast_tanh(h[q])) << (16 * q);
      *(uint64_t*)(hbuf + ((size_t)mybatch * T + t) * L + jc0) = hv;
    }
  }
}

// ---------------------------------------------------------------------
__launch_bounds__(256)
__global__ void out_gemm(const uint8_t* __restrict__ ws, float* __restrict__ out) {
  const short* hs  = (const short*)(ws + HBUF_OFF);
  const short* wot = (const short*)(ws + WOT_OFF);
  const int tid = threadIdx.x, lane = tid & 63, w = tid >> 6;
  const int wm = w >> 1, wn = w & 1;
  const int l15 = lane & 15, lhi = lane >> 4;
  const size_t m0 = (size_t)blockIdx.x * 128 + (size_t)wm * 64;

  f32x4 acc[4][4] = {};
  for (int kt = 0; kt < 32; ++kt) {
    s16x8 a[4], b[4];
    #pragma unroll
    for (int fi = 0; fi < 4; ++fi)
      a[fi] = *(const s16x8*)(hs + (m0 + fi * 16 + l15) * L + kt * 32 + lhi * 8);
    #pragma unroll
    for (int fj = 0; fj < 4; ++fj)
      b[fj] = *(const s16x8*)(wot + (size_t)(wn * 64 + fj * 16 + l15) * L + kt * 32 + lhi * 8);
    #pragma unroll
    for (int fi = 0; fi < 4; ++fi)
      #pragma unroll
      for (int fj = 0; fj < 4; ++fj)
        acc[fi][fj] = __builtin_amdgcn_mfma_f32_16x16x32_bf16(a[fi], b[fj], acc[fi][fj], 0, 0, 0);
  }
  #pragma unroll
  for (int fi = 0; fi < 4; ++fi)
    #pragma unroll
    for (int fj = 0; fj < 4; ++fj)
      #pragma unroll
      for (int q = 0; q < 4; ++q) {
        size_t m = m0 + fi * 16 + lhi * 4 + q;
        out[m * O + wn * 64 + fj * 16 + l15] = acc[fi][fj][q];
      }
}

__global__ void ws_too_small(float* out, int n) {
  int i = blockIdx.x * blockDim.x + threadIdx.x;
  if (i < n) out[i] = 12345.0f;
}

extern "C" void kernel_launch(void* const* d_in, const int* in_sizes, int n_in,
                              void* d_out, int out_size, void* d_ws, size_t ws_size,
                              hipStream_t stream) {
  const float* input = (const float*)d_in[0];
  const float* noise = (const float*)d_in[1];
  const float* wi    = (const float*)d_in[2];
  const float* si    = (const float*)d_in[3];
  const float* wrec  = (const float*)d_in[4];
  const float* bvec  = (const float*)d_in[5];
  const float* wo    = (const float*)d_in[6];
  const float* so    = (const float*)d_in[7];
  const float* h0    = (const float*)d_in[8];
  uint8_t* ws = (uint8_t*)d_ws;
  float* out = (float*)d_out;

  if (ws_size < WS_NEED) {
    ws_too_small<<<(out_size + 255) / 256, 256, 0, stream>>>(out, out_size);
    return;
  }

  pack_kernel<<<256, 256, 0, stream>>>(wi, si, wrec, wo, so, ws);
  rnn_kernel<<<NROW * NJB, 256, 0, stream>>>(input, noise, bvec, h0, ws);
  out_gemm<<<(B * T) / 128, 256, 0, stream>>>(ws, out);
}